// Round 8
// baseline (1655.510 us; speedup 1.0000x reference)
//
#include <hip/hip_runtime.h>
#include <hip/hip_cooperative_groups.h>
#include <float.h>
#include <math.h>

namespace cg = cooperative_groups;

#define B_ 32
#define S_ 2048
#define H_ 1024
#define M_ 128
#define N_ 500000
#define KK 16
#define KK2 32
#define ALPHA_ 0.1f
#define TAU_ 0.1f
#define EPS_ 1e-5f
#define MAX_NORM_ 0.99999f
#define MAXN2_ (MAX_NORM_ * MAX_NORM_)
#define SC_ 64
#define RPB_ 512
#define NBLK_ ((N_ + RPB_ - 1) / RPB_)   // 977
#define WIN_ 2048
#define NWIN_ ((N_ + WIN_ - 1) / WIN_)   // 245
#define NPAD_ (NWIN_ * WIN_)             // 501760
#define GRID_ 1024

typedef __attribute__((ext_vector_type(8))) short short8;
typedef __attribute__((ext_vector_type(4))) float f32x4;

__device__ __forceinline__ unsigned short to_bf16(float x) {
    unsigned u = __float_as_uint(x);
    return (unsigned short)((u + 0x7FFFu + ((u >> 16) & 1u)) >> 16); // RNE, monotone on +floats
}

// 256-thread block reduce; callers pass 0 for inactive lanes. All 256 must call.
__device__ __forceinline__ float bred256(float v, volatile float* red, int tid) {
    red[tid] = v;
    __syncthreads();
    if (tid < 64) {
        float x = red[tid] + red[tid + 64] + red[tid + 128] + red[tid + 192];
        #pragma unroll
        for (int off = 32; off >= 1; off >>= 1) x += __shfl_down(x, off);
        if (tid == 0) red[0] = x;
    }
    __syncthreads();
    float r = red[0];
    __syncthreads();
    return r;
}

// ================================================================ MEGA (cooperative)
__global__ __launch_bounds__(256, 4) void mega(
        const float* __restrict__ hid, const float* __restrict__ W1,
        const float* __restrict__ b1, const float* __restrict__ ln_g,
        const float* __restrict__ ln_b, const float* __restrict__ W2,
        const float* __restrict__ b2, const float* __restrict__ qorig,
        const float* __restrict__ mem, const float* __restrict__ Wp,
        const float* __restrict__ bp, float* __restrict__ out,
        float* __restrict__ pp, float* __restrict__ query, float* __restrict__ qstats,
        unsigned short* __restrict__ keyplane, unsigned* __restrict__ cand_key,
        float* __restrict__ force) {
    cg::grid_group grid = cg::this_grid();
    __shared__ __align__(16) char smem[18944];
    int tid = threadIdx.x;

    // ---------------- phase 1: pool partial sums (2 chunks per block)
    {
        const float4* h4 = (const float4*)hid;
        #pragma unroll
        for (int rep = 0; rep < 2; ++rep) {
            int chunk = blockIdx.x + rep * GRID_;    // = b*64 + sc
            int b = chunk >> 6, sc = chunk & 63;
            float4 acc = {0.f, 0.f, 0.f, 0.f};
            int s0 = sc * (S_ / SC_);
            for (int s = 0; s < S_ / SC_; ++s) {
                float4 v = h4[((size_t)(b * S_ + s0 + s) << 8) + tid];
                acc.x += v.x; acc.y += v.y; acc.z += v.z; acc.w += v.w;
            }
            ((float4*)pp)[(size_t)chunk * 256 + tid] = acc;
        }
    }
    __threadfence();
    grid.sync();

    // ---------------- phase 2: query network (blocks 0..31)
    if (blockIdx.x < B_) {
        int b = blockIdx.x;
        float* pooled = (float*)smem;          // 1024 f
        float* red    = pooled + H_;           // 256 f
        float* hv     = red + 256;             // 128 f
        #pragma unroll
        for (int j = 0; j < H_ / 256; ++j) {
            int h = tid + j * 256;
            float s = 0.f;
            for (int sc = 0; sc < SC_; ++sc) s += pp[(size_t)(b * SC_ + sc) * H_ + h];
            pooled[h] = s * (1.0f / (float)S_);
        }
        __syncthreads();
        int m = tid & 127, half = tid >> 7;
        float xp = 0.f;
        for (int k = half * (H_ / 2); k < (half + 1) * (H_ / 2); ++k)
            xp = fmaf(pooled[k], W1[k * M_ + m], xp);
        red[tid] = xp;
        __syncthreads();
        float x = (tid < M_) ? (red[m] + red[m + 128] + b1[m]) : 0.f;
        __syncthreads();
        float mu = bred256(x, red, tid) * (1.0f / (float)M_);
        float dmu = (tid < M_) ? (x - mu) : 0.f;
        float var = bred256(dmu * dmu, red, tid) * (1.0f / (float)M_);
        float lg = (tid < M_) ? ln_g[m] : 0.f;
        float lb = (tid < M_) ? ln_b[m] : 0.f;
        float xh = dmu * rsqrtf(var + 1e-5f) * lg + lb;
        float g = 0.5f * xh * (1.0f + erff(xh * 0.70710678f));
        if (tid < M_) hv[m] = g;
        __syncthreads();
        float t = 0.f;
        if (tid < M_) {
            t = b2[m];
            for (int k = 0; k < M_; ++k) t = fmaf(hv[k], W2[k * M_ + m], t);
        }
        float o = (tid < M_) ? qorig[m] : 0.f;
        float on2 = bred256(o * o, red, tid);
        float on = fmaxf(sqrtf(on2), EPS_);
        float osc = 1.0f / fmaxf(on / MAX_NORM_, 1.0f);
        float u = o * osc;
        float vn2 = bred256(t * t, red, tid);
        float vn = fmaxf(sqrtf(vn2), EPS_);
        float sec = tanhf(vn * 0.5f) * t / vn;
        float dot_uv = bred256(u * sec, red, tid);
        float nu = fminf(fmaxf(bred256(u * u, red, tid), 0.f), MAXN2_);
        float nv = fminf(fmaxf(bred256(sec * sec, red, tid), 0.f), MAXN2_);
        float num = (1.0f + 2.0f * dot_uv + nv) * u + (1.0f - nu) * sec;
        float den = 1.0f + 2.0f * dot_uv + nu * nv;
        float r = num / fmaxf(den, EPS_);
        float rn2 = bred256(r * r, red, tid);
        float rn = fmaxf(sqrtf(rn2), EPS_);
        float rsc = 1.0f / fmaxf(rn / MAX_NORM_, 1.0f);
        float q = r * rsc;
        if (tid < M_) query[b * M_ + m] = q;
        float qq = bred256(q * q, red, tid);
        if (tid == 0) {
            qstats[b * 2 + 0] = qq;
            float qn = fminf(fmaxf(qq, 0.f), MAXN2_);
            qstats[b * 2 + 1] = 1.0f - qn;
        }
    }
    __threadfence();
    grid.sync();

    // ---------------- phase 3: MFMA scorer -> ushort keyplane (blocks 0..976)
    if (blockIdx.x < NBLK_) {
        unsigned short (*key_lds)[264] = (unsigned short(*)[264])smem;     // 16896 B
        float* mm_lds = (float*)(smem + 16896);                            // 1024 B
        float* qq_s   = (float*)(smem + 16896 + 1024);                     // 128 B
        float* omq_s  = qq_s + B_;                                         // 128 B
        int bid = blockIdx.x;
        int wave = tid >> 6, lane = tid & 63;
        int l15 = lane & 15, lk = lane >> 4;

        if (tid < B_) { qq_s[tid] = qstats[tid * 2]; omq_s[tid] = qstats[tid * 2 + 1]; }

        short8 bfrag[2][4];
        #pragma unroll
        for (int bg = 0; bg < 2; ++bg) {
            #pragma unroll
            for (int kt = 0; kt < 4; ++kt) {
                int batch = bg * 16 + l15;
                const float4* qp = (const float4*)(query + batch * M_ + kt * 32 + lk * 8);
                float4 lo = qp[0], hi = qp[1];
                short8 f;
                f[0] = (short)to_bf16(lo.x); f[1] = (short)to_bf16(lo.y);
                f[2] = (short)to_bf16(lo.z); f[3] = (short)to_bf16(lo.w);
                f[4] = (short)to_bf16(hi.x); f[5] = (short)to_bf16(hi.y);
                f[6] = (short)to_bf16(hi.z); f[7] = (short)to_bf16(hi.w);
                bfrag[bg][kt] = f;
            }
        }

        #pragma unroll 1
        for (int p = 0; p < 2; ++p) {
            int passbase = bid * RPB_ + p * 256;
            f32x4 acc[4][2];
            #pragma unroll
            for (int rg = 0; rg < 4; ++rg)
                #pragma unroll
                for (int bg = 0; bg < 2; ++bg)
                    acc[rg][bg] = (f32x4){0.f, 0.f, 0.f, 0.f};
            float mmp[4] = {0.f, 0.f, 0.f, 0.f};

            #pragma unroll
            for (int rg = 0; rg < 4; ++rg) {
                int r = passbase + wave * 64 + rg * 16 + l15;
                const float4* mp = (const float4*)(mem + (size_t)((r < N_) ? r : 0) * M_);
                #pragma unroll
                for (int kt = 0; kt < 4; ++kt) {
                    float4 lo = mp[kt * 8 + lk * 2];
                    float4 hi = mp[kt * 8 + lk * 2 + 1];
                    mmp[rg] = fmaf(lo.x, lo.x, fmaf(lo.y, lo.y, fmaf(lo.z, lo.z, fmaf(lo.w, lo.w, mmp[rg]))));
                    mmp[rg] = fmaf(hi.x, hi.x, fmaf(hi.y, hi.y, fmaf(hi.z, hi.z, fmaf(hi.w, hi.w, mmp[rg]))));
                    short8 af;
                    af[0] = (short)to_bf16(lo.x); af[1] = (short)to_bf16(lo.y);
                    af[2] = (short)to_bf16(lo.z); af[3] = (short)to_bf16(lo.w);
                    af[4] = (short)to_bf16(hi.x); af[5] = (short)to_bf16(hi.y);
                    af[6] = (short)to_bf16(hi.z); af[7] = (short)to_bf16(hi.w);
                    acc[rg][0] = __builtin_amdgcn_mfma_f32_16x16x32_bf16(af, bfrag[0][kt], acc[rg][0], 0, 0, 0);
                    acc[rg][1] = __builtin_amdgcn_mfma_f32_16x16x32_bf16(af, bfrag[1][kt], acc[rg][1], 0, 0, 0);
                }
            }
            #pragma unroll
            for (int rg = 0; rg < 4; ++rg) {
                float v = mmp[rg] + __shfl_xor(mmp[rg], 16);
                v += __shfl_xor(v, 32);
                if (lane < 16) mm_lds[wave * 64 + rg * 16 + l15] = v;
            }
            __syncthreads();

            #pragma unroll
            for (int rg = 0; rg < 4; ++rg) {
                #pragma unroll
                for (int bg = 0; bg < 2; ++bg) {
                    #pragma unroll
                    for (int reg = 0; reg < 4; ++reg) {
                        int row_local = wave * 64 + rg * 16 + lk * 4 + reg;
                        int batch = bg * 16 + l15;
                        float dot = acc[rg][bg][reg];
                        float mmv = mm_lds[row_local];
                        float mn = fminf(mmv, MAXN2_);
                        float dsq = fmaxf(qq_s[batch] + mmv - 2.0f * dot, 0.f);
                        float t = dsq / fmaxf(omq_s[batch] * (1.0f - mn), EPS_);
                        key_lds[batch][row_local] = to_bf16(t);
                    }
                }
            }
            __syncthreads();

            {
                int batch = tid >> 3, chunk = tid & 7;
                int rbase = passbase + chunk * 32;
                unsigned short* dstp = keyplane + (size_t)batch * NPAD_ + rbase;
                #pragma unroll
                for (int i = 0; i < 4; ++i) {
                    int gr = rbase + i * 8;
                    uint4 v = *(const uint4*)&key_lds[batch][chunk * 32 + i * 8];
                    if (gr + 8 <= N_) {
                        *(uint4*)(dstp + i * 8) = v;
                    } else {
                        for (int t = 0; t < 8; ++t)
                            if (gr + t < N_) dstp[i * 8 + t] = key_lds[batch][chunk * 32 + i * 8 + t];
                    }
                }
            }
            __syncthreads();
        }
    }
    __threadfence();
    grid.sync();

    // ---------------- phase 4: per-window top-16 (blocks 0..979)
    if (blockIdx.x < NWIN_ * 4) {
        int win = blockIdx.x >> 2, quad = blockIdx.x & 3;
        int wave = tid >> 6, lane = tid & 63;
        int base = win * WIN_;
        #pragma unroll 1
        for (int j = 0; j < 2; ++j) {
            int b = quad * 8 + wave * 2 + j;
            const uint4* kp = (const uint4*)(keyplane + (size_t)b * NPAD_ + base);
            unsigned keys[32];
            #pragma unroll
            for (int i = 0; i < 4; ++i) {
                uint4 v = kp[lane + i * 64];
                int rl0 = (lane + i * 64) * 8;
                int pos = base + rl0;
                unsigned s[8];
                s[0] = v.x & 0xFFFFu; s[1] = v.x >> 16;
                s[2] = v.y & 0xFFFFu; s[3] = v.y >> 16;
                s[4] = v.z & 0xFFFFu; s[5] = v.z >> 16;
                s[6] = v.w & 0xFFFFu; s[7] = v.w >> 16;
                #pragma unroll
                for (int t = 0; t < 8; ++t)
                    keys[i * 8 + t] = (pos + t < N_) ? ((s[t] << 11) | (unsigned)(rl0 + t))
                                                     : 0xFFFFFFFFu;
            }
            for (int k = 0; k < KK; ++k) {
                unsigned m = keys[0];
                #pragma unroll
                for (int i = 1; i < 32; ++i) m = min(m, keys[i]);
                #pragma unroll
                for (int off = 32; off >= 1; off >>= 1)
                    m = min(m, (unsigned)__shfl_xor((int)m, off));
                if (lane == 0) cand_key[((size_t)win * B_ + b) * KK + k] = m;
                #pragma unroll
                for (int i = 0; i < 32; ++i)
                    if (keys[i] == m) keys[i] = 0xFFFFFFFFu;
            }
        }
    }
    __threadfence();
    grid.sync();

    // ---------------- phase 5: merge->32, exact dists, top-16, softmax, retrieve, force (blocks 0..31)
    if (blockIdx.x < B_) {
        int b = blockIdx.x;
        int* top32_s = (int*)smem;               // 128 B
        float* q_s   = (float*)(smem + 128);     // 512 B
        float* d_s   = (float*)(smem + 640);     // 128 B
        float* w_s   = (float*)(smem + 768);     // 64 B
        int* idx_s   = (int*)(smem + 832);       // 64 B
        float* ret_s = (float*)(smem + 896);     // 512 B
        if (tid < M_) q_s[tid] = query[b * M_ + tid];

        if (tid < 64) {
            unsigned long long vals[16];
            #pragma unroll
            for (int i = 0; i < 16; ++i) vals[i] = 0xFFFFFFFFFFFFFFFFull;
            for (int c = tid; c < NWIN_ * KK; c += 64) {
                int g = c >> 4, k = c & 15;
                unsigned v = cand_key[((size_t)g * B_ + b) * KK + k];
                unsigned grow = (unsigned)(g * WIN_) + (v & 2047u);
                unsigned long long key = ((unsigned long long)v << 32) | (unsigned long long)grow;
                if (key < vals[15]) {
                    vals[15] = key;
                    #pragma unroll
                    for (int j = 15; j > 0; --j) {
                        if (vals[j] < vals[j - 1]) {
                            unsigned long long tt = vals[j]; vals[j] = vals[j - 1]; vals[j - 1] = tt;
                        }
                    }
                }
            }
            for (int k = 0; k < KK2; ++k) {
                unsigned long long m = vals[0];
                #pragma unroll
                for (int off = 32; off >= 1; off >>= 1) {
                    unsigned long long o = __shfl_xor(m, off);
                    if (o < m) m = o;
                }
                if (tid == 0) {
                    int ci = (int)(unsigned)(m & 0xFFFFFFFFull);
                    top32_s[k] = (ci < 0) ? 0 : ((ci >= N_) ? (N_ - 1) : ci);
                }
                if (vals[0] == m) {
                    #pragma unroll
                    for (int j = 0; j < 15; ++j) vals[j] = vals[j + 1];
                    vals[15] = 0xFFFFFFFFFFFFFFFFull;
                }
            }
        }
        __syncthreads();

        float qq = qstats[b * 2], omq = qstats[b * 2 + 1];
        int wave = tid >> 6, lane = tid & 63;
        for (int ii = wave; ii < KK2; ii += 4) {
            const float* mr = mem + (size_t)top32_s[ii] * M_;
            float a0 = mr[lane], a1 = mr[lane + 64];
            float p = q_s[lane] * a0 + q_s[lane + 64] * a1;
            float mm = a0 * a0 + a1 * a1;
            #pragma unroll
            for (int off = 32; off >= 1; off >>= 1) {
                p += __shfl_down(p, off);
                mm += __shfl_down(mm, off);
            }
            if (lane == 0) {
                float dsq = fmaxf(qq + mm - 2.0f * p, 0.f);
                float mn = fminf(mm, MAXN2_);
                float t = dsq / fmaxf(omq * (1.0f - mn), EPS_);
                d_s[ii] = acoshf(1.0f + 2.0f * t);
            }
        }
        __syncthreads();
        if (tid == 0) {
            bool used[KK2];
            for (int i = 0; i < KK2; ++i) used[i] = false;
            float seld[KK];
            for (int k = 0; k < KK; ++k) {
                float bd = FLT_MAX; int bi = -1;
                for (int i = 0; i < KK2; ++i) {
                    if (used[i]) continue;
                    if (d_s[i] < bd || (d_s[i] == bd && (bi < 0 || top32_s[i] < top32_s[bi]))) {
                        bd = d_s[i]; bi = i;
                    }
                }
                used[bi] = true; seld[k] = bd; idx_s[k] = top32_s[bi];
            }
            float dmin = seld[0];
            for (int i = 1; i < KK; ++i) dmin = fminf(dmin, seld[i]);
            float Z = 0.f;
            for (int i = 0; i < KK; ++i) {
                float w = expf((dmin - seld[i]) * (1.0f / TAU_));
                w_s[i] = w; Z += w;
            }
            float iZ = 1.0f / Z;
            for (int i = 0; i < KK; ++i) w_s[i] *= iZ;
        }
        __syncthreads();
        if (tid < M_) {
            float r = 0.f;
            for (int i = 0; i < KK; ++i) r = fmaf(w_s[i], mem[(size_t)idx_s[i] * M_ + tid], r);
            ret_s[tid] = r;
        }
        __syncthreads();
        #pragma unroll
        for (int j = 0; j < 4; ++j) {
            int h = tid + j * 256;
            float f = bp[h];
            for (int k = 0; k < M_; ++k) f = fmaf(ret_s[k], Wp[k * H_ + h], f);
            force[b * H_ + h] = f;
        }
    }
    __threadfence();
    grid.sync();

    // ---------------- phase 6: out = hidden + alpha*force
    {
        const float4* h4 = (const float4*)hid;
        const float4* f4 = (const float4*)force;
        float4* o4 = (float4*)out;
        int n4 = B_ * S_ * H_ / 4;
        for (int i = blockIdx.x * 256 + tid; i < n4; i += GRID_ * 256) {
            int b = i >> 19;
            float4 hv = h4[i];
            float4 fv = f4[(b << 8) + (i & 255)];
            float4 ov;
            ov.x = fmaf(ALPHA_, fv.x, hv.x);
            ov.y = fmaf(ALPHA_, fv.y, hv.y);
            ov.z = fmaf(ALPHA_, fv.z, hv.z);
            ov.w = fmaf(ALPHA_, fv.w, hv.w);
            o4[i] = ov;
        }
    }
}

// ================================================================ FALLBACK (R7 kernels, verified)
__global__ __launch_bounds__(256) void k1_pool(const float* __restrict__ hid,
                                               float* __restrict__ pp) {
    int bid = blockIdx.x;
    int b = bid >> 6, sc = bid & 63;
    const float4* h4 = (const float4*)hid;
    float4 acc = {0.f, 0.f, 0.f, 0.f};
    int s0 = sc * (S_ / SC_);
    for (int s = 0; s < S_ / SC_; ++s) {
        float4 v = h4[((size_t)(b * S_ + s0 + s) << 8) + threadIdx.x];
        acc.x += v.x; acc.y += v.y; acc.z += v.z; acc.w += v.w;
    }
    ((float4*)pp)[(size_t)(b * SC_ + sc) * 256 + threadIdx.x] = acc;
}

__device__ __forceinline__ float block_reduce_sum_128(float v, volatile float* red, int tid) {
    red[tid] = v;
    __syncthreads();
    if (tid < 64) red[tid] += red[tid + 64];
    __syncthreads();
    if (tid < 64) {
        float x = red[tid];
        #pragma unroll
        for (int off = 32; off >= 1; off >>= 1) x += __shfl_down(x, off);
        if (tid == 0) red[0] = x;
    }
    __syncthreads();
    float r = red[0];
    __syncthreads();
    return r;
}

__global__ void k2_query(const float* __restrict__ pp, const float* __restrict__ W1,
                         const float* __restrict__ b1, const float* __restrict__ ln_g,
                         const float* __restrict__ ln_b, const float* __restrict__ W2,
                         const float* __restrict__ b2, const float* __restrict__ qorig,
                         float* __restrict__ query, float* __restrict__ qstats) {
    __shared__ float pooled[H_];
    __shared__ float red[128];
    __shared__ float hv[M_];
    int b = blockIdx.x, tid = threadIdx.x;
    #pragma unroll
    for (int j = 0; j < H_ / 128; ++j) {
        int h = tid + j * 128;
        float s = 0.f;
        for (int sc = 0; sc < SC_; ++sc) s += pp[(size_t)(b * SC_ + sc) * H_ + h];
        pooled[h] = s * (1.0f / (float)S_);
    }
    __syncthreads();
    int m = tid;
    float x = b1[m];
    for (int k = 0; k < H_; ++k) x = fmaf(pooled[k], W1[k * M_ + m], x);
    float mu = block_reduce_sum_128(x, red, tid) * (1.0f / (float)M_);
    float dmu = x - mu;
    float var = block_reduce_sum_128(dmu * dmu, red, tid) * (1.0f / (float)M_);
    float xh = dmu * rsqrtf(var + 1e-5f) * ln_g[m] + ln_b[m];
    float g = 0.5f * xh * (1.0f + erff(xh * 0.70710678f));
    hv[m] = g;
    __syncthreads();
    float t = b2[m];
    for (int k = 0; k < M_; ++k) t = fmaf(hv[k], W2[k * M_ + m], t);
    float o = qorig[m];
    float on2 = block_reduce_sum_128(o * o, red, tid);
    float on = fmaxf(sqrtf(on2), EPS_);
    float osc = 1.0f / fmaxf(on / MAX_NORM_, 1.0f);
    float u = o * osc;
    float vn2 = block_reduce_sum_128(t * t, red, tid);
    float vn = fmaxf(sqrtf(vn2), EPS_);
    float sec = tanhf(vn * 0.5f) * t / vn;
    float dot_uv = block_reduce_sum_128(u * sec, red, tid);
    float nu = fminf(fmaxf(block_reduce_sum_128(u * u, red, tid), 0.f), MAXN2_);
    float nv = fminf(fmaxf(block_reduce_sum_128(sec * sec, red, tid), 0.f), MAXN2_);
    float num = (1.0f + 2.0f * dot_uv + nv) * u + (1.0f - nu) * sec;
    float den = 1.0f + 2.0f * dot_uv + nu * nv;
    float r = num / fmaxf(den, EPS_);
    float rn2 = block_reduce_sum_128(r * r, red, tid);
    float rn = fmaxf(sqrtf(rn2), EPS_);
    float rsc = 1.0f / fmaxf(rn / MAX_NORM_, 1.0f);
    float q = r * rsc;
    query[b * M_ + m] = q;
    float qq = block_reduce_sum_128(q * q, red, tid);
    if (tid == 0) {
        qstats[b * 2 + 0] = qq;
        float qn = fminf(fmaxf(qq, 0.f), MAXN2_);
        qstats[b * 2 + 1] = 1.0f - qn;
    }
}

__global__ __launch_bounds__(256, 3) void k3_scores(const float* __restrict__ mem,
                                                    const float* __restrict__ query,
                                                    const float* __restrict__ qstats,
                                                    unsigned short* __restrict__ keyplane) {
    __shared__ unsigned short key_lds[B_][264];
    __shared__ float mm_lds[256];
    __shared__ float qq_s[B_], omq_s[B_];
    int tid = threadIdx.x, bid = blockIdx.x;
    int wave = tid >> 6, lane = tid & 63;
    int l15 = lane & 15, lk = lane >> 4;

    if (tid < B_) { qq_s[tid] = qstats[tid * 2]; omq_s[tid] = qstats[tid * 2 + 1]; }

    short8 bfrag[2][4];
    #pragma unroll
    for (int bg = 0; bg < 2; ++bg) {
        #pragma unroll
        for (int kt = 0; kt < 4; ++kt) {
            int batch = bg * 16 + l15;
            const float4* qp = (const float4*)(query + batch * M_ + kt * 32 + lk * 8);
            float4 lo = qp[0], hi = qp[1];
            short8 f;
            f[0] = (short)to_bf16(lo.x); f[1] = (short)to_bf16(lo.y);
            f[2] = (short)to_bf16(lo.z); f[3] = (short)to_bf16(lo.w);
            f[4] = (short)to_bf16(hi.x); f[5] = (short)to_bf16(hi.y);
            f[6] = (short)to_bf16(hi.z); f[7] = (short)to_bf16(hi.w);
            bfrag[bg][kt] = f;
        }
    }

    #pragma unroll 1
    for (int p = 0; p < 2; ++p) {
        int passbase = bid * RPB_ + p * 256;
        f32x4 acc[4][2];
        #pragma unroll
        for (int rg = 0; rg < 4; ++rg)
            #pragma unroll
            for (int bg = 0; bg < 2; ++bg)
                acc[rg][bg] = (f32x4){0.f, 0.f, 0.f, 0.f};
        float mmp[4] = {0.f, 0.f, 0.f, 0.f};

        #pragma unroll
        for (int rg = 0; rg < 4; ++rg) {
            int r = passbase + wave * 64 + rg * 16 + l15;
            const float4* mp = (const float4*)(mem + (size_t)((r < N_) ? r : 0) * M_);
            #pragma unroll
            for (int kt = 0; kt < 4; ++kt) {
                float4 lo = mp[kt * 8 + lk * 2];
                float4 hi = mp[kt * 8 + lk * 2 + 1];
                mmp[rg] = fmaf(lo.x, lo.x, fmaf(lo.y, lo.y, fmaf(lo.z, lo.z, fmaf(lo.w, lo.w, mmp[rg]))));
                mmp[rg] = fmaf(hi.x, hi.x, fmaf(hi.y, hi.y, fmaf(hi.z, hi.z, fmaf(hi.w, hi.w, mmp[rg]))));
                short8 af;
                af[0] = (short)to_bf16(lo.x); af[1] = (short)to_bf16(lo.y);
                af[2] = (short)to_bf16(lo.z); af[3] = (short)to_bf16(lo.w);
                af[4] = (short)to_bf16(hi.x); af[5] = (short)to_bf16(hi.y);
                af[6] = (short)to_bf16(hi.z); af[7] = (short)to_bf16(hi.w);
                acc[rg][0] = __builtin_amdgcn_mfma_f32_16x16x32_bf16(af, bfrag[0][kt], acc[rg][0], 0, 0, 0);
                acc[rg][1] = __builtin_amdgcn_mfma_f32_16x16x32_bf16(af, bfrag[1][kt], acc[rg][1], 0, 0, 0);
            }
        }
        #pragma unroll
        for (int rg = 0; rg < 4; ++rg) {
            float v = mmp[rg] + __shfl_xor(mmp[rg], 16);
            v += __shfl_xor(v, 32);
            if (lane < 16) mm_lds[wave * 64 + rg * 16 + l15] = v;
        }
        __syncthreads();

        #pragma unroll
        for (int rg = 0; rg < 4; ++rg) {
            #pragma unroll
            for (int bg = 0; bg < 2; ++bg) {
                #pragma unroll
                for (int reg = 0; reg < 4; ++reg) {
                    int row_local = wave * 64 + rg * 16 + lk * 4 + reg;
                    int batch = bg * 16 + l15;
                    float dot = acc[rg][bg][reg];
                    float mmv = mm_lds[row_local];
                    float mn = fminf(mmv, MAXN2_);
                    float dsq = fmaxf(qq_s[batch] + mmv - 2.0f * dot, 0.f);
                    float t = dsq / fmaxf(omq_s[batch] * (1.0f - mn), EPS_);
                    key_lds[batch][row_local] = to_bf16(t);
                }
            }
        }
        __syncthreads();

        {
            int batch = tid >> 3, chunk = tid & 7;
            int rbase = passbase + chunk * 32;
            unsigned short* dstp = keyplane + (size_t)batch * NPAD_ + rbase;
            #pragma unroll
            for (int i = 0; i < 4; ++i) {
                int gr = rbase + i * 8;
                uint4 v = *(const uint4*)&key_lds[batch][chunk * 32 + i * 8];
                if (gr + 8 <= N_) {
                    *(uint4*)(dstp + i * 8) = v;
                } else {
                    for (int t = 0; t < 8; ++t)
                        if (gr + t < N_) dstp[i * 8 + t] = key_lds[batch][chunk * 32 + i * 8 + t];
                }
            }
        }
        __syncthreads();
    }
}

__global__ __launch_bounds__(256, 4) void k4_sel(const unsigned short* __restrict__ keyplane,
                                                 unsigned* __restrict__ cand_key) {
    int win = blockIdx.x >> 2, quad = blockIdx.x & 3;
    int wave = threadIdx.x >> 6, lane = threadIdx.x & 63;
    int base = win * WIN_;
    #pragma unroll 1
    for (int j = 0; j < 2; ++j) {
        int b = quad * 8 + wave * 2 + j;
        const uint4* kp = (const uint4*)(keyplane + (size_t)b * NPAD_ + base);
        unsigned keys[32];
        #pragma unroll
        for (int i = 0; i < 4; ++i) {
            uint4 v = kp[lane + i * 64];
            int rl0 = (lane + i * 64) * 8;
            int pos = base + rl0;
            unsigned s[8];
            s[0] = v.x & 0xFFFFu; s[1] = v.x >> 16;
            s[2] = v.y & 0xFFFFu; s[3] = v.y >> 16;
            s[4] = v.z & 0xFFFFu; s[5] = v.z >> 16;
            s[6] = v.w & 0xFFFFu; s[7] = v.w >> 16;
            #pragma unroll
            for (int t = 0; t < 8; ++t)
                keys[i * 8 + t] = (pos + t < N_) ? ((s[t] << 11) | (unsigned)(rl0 + t))
                                                 : 0xFFFFFFFFu;
        }
        for (int k = 0; k < KK; ++k) {
            unsigned m = keys[0];
            #pragma unroll
            for (int i = 1; i < 32; ++i) m = min(m, keys[i]);
            #pragma unroll
            for (int off = 32; off >= 1; off >>= 1)
                m = min(m, (unsigned)__shfl_xor((int)m, off));
            if (lane == 0) cand_key[((size_t)win * B_ + b) * KK + k] = m;
            #pragma unroll
            for (int i = 0; i < 32; ++i)
                if (keys[i] == m) keys[i] = 0xFFFFFFFFu;
        }
    }
}

__global__ void k45_retrieve(const unsigned* __restrict__ cand_key,
                             const float* __restrict__ mem, const float* __restrict__ query,
                             const float* __restrict__ qstats,
                             const float* __restrict__ Wp, const float* __restrict__ bp,
                             float* __restrict__ force) {
    __shared__ int top32_s[KK2];
    __shared__ float q_s[M_];
    __shared__ float d_s[KK2];
    __shared__ float w_s[KK];
    __shared__ int idx_s[KK];
    __shared__ float ret_s[M_];
    int b = blockIdx.x, tid = threadIdx.x;
    if (tid < M_) q_s[tid] = query[b * M_ + tid];

    if (tid < 64) {
        unsigned long long vals[16];
        #pragma unroll
        for (int i = 0; i < 16; ++i) vals[i] = 0xFFFFFFFFFFFFFFFFull;
        for (int c = tid; c < NWIN_ * KK; c += 64) {
            int g = c >> 4, k = c & 15;
            unsigned v = cand_key[((size_t)g * B_ + b) * KK + k];
            unsigned grow = (unsigned)(g * WIN_) + (v & 2047u);
            unsigned long long key = ((unsigned long long)v << 32) | (unsigned long long)grow;
            if (key < vals[15]) {
                vals[15] = key;
                #pragma unroll
                for (int j = 15; j > 0; --j) {
                    if (vals[j] < vals[j - 1]) {
                        unsigned long long tt = vals[j]; vals[j] = vals[j - 1]; vals[j - 1] = tt;
                    }
                }
            }
        }
        for (int k = 0; k < KK2; ++k) {
            unsigned long long m = vals[0];
            #pragma unroll
            for (int off = 32; off >= 1; off >>= 1) {
                unsigned long long o = __shfl_xor(m, off);
                if (o < m) m = o;
            }
            if (tid == 0) {
                int ci = (int)(unsigned)(m & 0xFFFFFFFFull);
                top32_s[k] = (ci < 0) ? 0 : ((ci >= N_) ? (N_ - 1) : ci);
            }
            if (vals[0] == m) {
                #pragma unroll
                for (int j = 0; j < 15; ++j) vals[j] = vals[j + 1];
                vals[15] = 0xFFFFFFFFFFFFFFFFull;
            }
        }
    }
    __syncthreads();

    float qq = qstats[b * 2], omq = qstats[b * 2 + 1];
    int wave = tid >> 6, lane = tid & 63;
    for (int ii = wave; ii < KK2; ii += 4) {
        const float* mr = mem + (size_t)top32_s[ii] * M_;
        float a0 = mr[lane], a1 = mr[lane + 64];
        float p = q_s[lane] * a0 + q_s[lane + 64] * a1;
        float mm = a0 * a0 + a1 * a1;
        #pragma unroll
        for (int off = 32; off >= 1; off >>= 1) {
            p += __shfl_down(p, off);
            mm += __shfl_down(mm, off);
        }
        if (lane == 0) {
            float dsq = fmaxf(qq + mm - 2.0f * p, 0.f);
            float mn = fminf(mm, MAXN2_);
            float t = dsq / fmaxf(omq * (1.0f - mn), EPS_);
            d_s[ii] = acoshf(1.0f + 2.0f * t);
        }
    }
    __syncthreads();
    if (tid == 0) {
        bool used[KK2];
        for (int i = 0; i < KK2; ++i) used[i] = false;
        float seld[KK];
        for (int k = 0; k < KK; ++k) {
            float bd = FLT_MAX; int bi = -1;
            for (int i = 0; i < KK2; ++i) {
                if (used[i]) continue;
                if (d_s[i] < bd || (d_s[i] == bd && (bi < 0 || top32_s[i] < top32_s[bi]))) {
                    bd = d_s[i]; bi = i;
                }
            }
            used[bi] = true; seld[k] = bd; idx_s[k] = top32_s[bi];
        }
        float dmin = seld[0];
        for (int i = 1; i < KK; ++i) dmin = fminf(dmin, seld[i]);
        float Z = 0.f;
        for (int i = 0; i < KK; ++i) {
            float w = expf((dmin - seld[i]) * (1.0f / TAU_));
            w_s[i] = w; Z += w;
        }
        float iZ = 1.0f / Z;
        for (int i = 0; i < KK; ++i) w_s[i] *= iZ;
    }
    __syncthreads();
    if (tid < M_) {
        float r = 0.f;
        for (int i = 0; i < KK; ++i) r = fmaf(w_s[i], mem[(size_t)idx_s[i] * M_ + tid], r);
        ret_s[tid] = r;
    }
    __syncthreads();
    #pragma unroll
    for (int j = 0; j < 4; ++j) {
        int h = tid + j * 256;
        float f = bp[h];
        for (int k = 0; k < M_; ++k) f = fmaf(ret_s[k], Wp[k * H_ + h], f);
        force[b * H_ + h] = f;
    }
}

__global__ __launch_bounds__(256) void k6_out(const float* __restrict__ hid,
                                              const float* __restrict__ force,
                                              float* __restrict__ out) {
    const float4* h4 = (const float4*)hid;
    const float4* f4 = (const float4*)force;
    float4* o4 = (float4*)out;
    int n4 = B_ * S_ * H_ / 4;
    for (int i = blockIdx.x * blockDim.x + threadIdx.x; i < n4; i += gridDim.x * blockDim.x) {
        int b = i >> 19;
        float4 hv = h4[i];
        float4 fv = f4[(b << 8) + (i & 255)];
        float4 ov;
        ov.x = fmaf(ALPHA_, fv.x, hv.x);
        ov.y = fmaf(ALPHA_, fv.y, hv.y);
        ov.z = fmaf(ALPHA_, fv.z, hv.z);
        ov.w = fmaf(ALPHA_, fv.w, hv.w);
        o4[i] = ov;
    }
}

// ================================================================ launch
extern "C" void kernel_launch(void* const* d_in, const int* in_sizes, int n_in,
                              void* d_out, int out_size, void* d_ws, size_t ws_size,
                              hipStream_t stream) {
    const float* hid    = (const float*)d_in[0];
    const float* W1     = (const float*)d_in[1];
    const float* b1     = (const float*)d_in[2];
    const float* ln_g   = (const float*)d_in[3];
    const float* ln_b   = (const float*)d_in[4];
    const float* W2     = (const float*)d_in[5];
    const float* b2     = (const float*)d_in[6];
    const float* qorig  = (const float*)d_in[7];
    const float* mem    = (const float*)d_in[8];
    const float* Wp     = (const float*)d_in[9];
    const float* bp     = (const float*)d_in[10];
    float* outp = (float*)d_out;

    char* ws = (char*)d_ws;
    size_t off = 0;
    float* pp = (float*)(ws + off);        off += (size_t)B_ * SC_ * H_ * 4;
    float* query = (float*)(ws + off);     off += (size_t)B_ * M_ * 4;
    float* qstats = (float*)(ws + off);    off += (size_t)B_ * 2 * 4;
    off = (off + 255) & ~(size_t)255;
    unsigned short* keyplane = (unsigned short*)(ws + off); off += (size_t)B_ * NPAD_ * 2;
    off = (off + 255) & ~(size_t)255;
    unsigned* cand_key = (unsigned*)(ws + off); off += (size_t)NWIN_ * B_ * KK * 4;
    float* force = (float*)(ws + off);     off += (size_t)B_ * H_ * 4;
    (void)ws_size; (void)in_sizes; (void)n_in; (void)out_size;

    void* args[] = {(void*)&hid, (void*)&W1, (void*)&b1, (void*)&ln_g, (void*)&ln_b,
                    (void*)&W2, (void*)&b2, (void*)&qorig, (void*)&mem, (void*)&Wp,
                    (void*)&bp, (void*)&outp, (void*)&pp, (void*)&query, (void*)&qstats,
                    (void*)&keyplane, (void*)&cand_key, (void*)&force};
    hipError_t err = hipLaunchCooperativeKernel((const void*)mega, dim3(GRID_), dim3(256),
                                                args, 0, stream);
    if (err != hipSuccess) {
        // deterministic fallback: proven 6-kernel path
        hipLaunchKernelGGL(k1_pool, dim3(B_ * SC_), dim3(256), 0, stream, hid, pp);
        hipLaunchKernelGGL(k2_query, dim3(B_), dim3(128), 0, stream, pp, W1, b1, ln_g, ln_b,
                           W2, b2, qorig, query, qstats);
        hipLaunchKernelGGL(k3_scores, dim3(NBLK_), dim3(256), 0, stream, mem, query, qstats, keyplane);
        hipLaunchKernelGGL(k4_sel, dim3(NWIN_ * 4), dim3(256), 0, stream, keyplane, cand_key);
        hipLaunchKernelGGL(k45_retrieve, dim3(B_), dim3(256), 0, stream, cand_key,
                           mem, query, qstats, Wp, bp, force);
        hipLaunchKernelGGL(k6_out, dim3(2048), dim3(256), 0, stream, hid, force, outp);
    }
}